// Round 5
// baseline (678.423 us; speedup 1.0000x reference)
//
#include <hip/hip_runtime.h>
#include <math.h>

#define BATCH 8192
#define D_G   4611
#define DGP   4624   // padded Wcat row stride
#define KN    25
#define KE    28     // padded pair-row: 25 weights, [25]=alpha slot, [26..27]=0

// workspace offsets (floats)
#define WS_WCAT   0         // [25][4624]
#define WS_BCAT   115600    // [4624]
#define WS_M      120224    // [25][25]
#define WS_C      120864    // [25]
#define WS_BB     120896    // [1]
#define WS_PPAD   120928    // [8192][28]  [25] = -q/2
#define WS_Q      350304    // [8192]
#define WS_G2     358496    // [8192]
#define WS_RPAD   366688    // [8192][28]  [25] = -T/2
#define WS_WP2    596064    // [8192] min sq bits (prior->G)
#define WS_WW2    604256    // [8192] min sq bits (G->G, i!=j)
#define WS_ACC    612448    // recon accumulator
#define WS_RACCP  612480    // [16][28][8192] prior-GEMM partials (dead after fin)
#define WS_H1T    612480    // [64][8192]  (aliases RACCP - used after fin)
#define WS_H2T    1136768   // [64][8192]  (aliases RACCP)

__device__ inline float eluf(float x) { return x > 0.f ? x : expm1f(x); }

__global__ void k_init(float* ws) {
  int idx = blockIdx.x * 256 + threadIdx.x;
  unsigned int* u = (unsigned int*)ws;
  if (idx < BATCH)            u[WS_WP2 + idx] = 0x7F7FFFFFu;
  else if (idx < 2 * BATCH)   u[WS_WW2 + (idx - BATCH)] = 0x7F7FFFFFu;
  else if (idx == 2 * BATCH)  ws[WS_ACC] = 0.f;
}

__global__ void k_build(const float* __restrict__ w1W, const float* __restrict__ w1b,
                        const float* __restrict__ b1W, const float* __restrict__ b1b,
                        const float* __restrict__ w2W, const float* __restrict__ w2b,
                        const float* __restrict__ b2W, const float* __restrict__ b2b,
                        const float* __restrict__ w3W, const float* __restrict__ w3b,
                        const float* __restrict__ b3W, const float* __restrict__ b3b,
                        float* ws) {
  int idx = blockIdx.x * 256 + threadIdx.x;
  if (idx >= KN * D_G) return;
  int k = idx / D_G;
  int d = idx - k * D_G;
  float wv, bv;
  if (d < 192)       { int c = d;        wv = w1W[k*192  + c]; bv = w1b[c]; }
  else if (d < 256)  { int c = d - 192;  wv = b1W[k*64   + c]; bv = b1b[c]; }
  else if (d < 4352) { int c = d - 256;  wv = w2W[k*4096 + c]; bv = w2b[c]; }
  else if (d < 4416) { int c = d - 4352; wv = b2W[k*64   + c]; bv = b2b[c]; }
  else if (d < 4608) { int c = d - 4416; wv = w3W[k*192  + c]; bv = w3b[c]; }
  else               { int c = d - 4608; wv = b3W[k*3    + c]; bv = b3b[c]; }
  ws[WS_WCAT + k * DGP + d] = wv;
  if (k == 0) ws[WS_BCAT + d] = bv;
}

// M = Wcat Wcat^T (25x25), c = Wcat bcat, bb = |bcat|^2
__global__ __launch_bounds__(256) void k_M(float* ws) {
  const float* Wc = ws + WS_WCAT;
  const float* bc = ws + WS_BCAT;
  __shared__ float part[4][26];
  int a = blockIdx.x, t = threadIdx.x;
  int wv = t >> 6, l = t & 63;
  if (a < 25) {
    float acc[26];
#pragma unroll
    for (int v = 0; v < 26; v++) acc[v] = 0.f;
    for (int d = t; d < D_G; d += 256) {
      float va = Wc[a * DGP + d];
#pragma unroll
      for (int b = 0; b < 25; b++) acc[b] += va * Wc[b * DGP + d];
      acc[25] += va * bc[d];
    }
#pragma unroll
    for (int v = 0; v < 26; v++) {
      float x = acc[v];
#pragma unroll
      for (int off = 32; off > 0; off >>= 1) x += __shfl_down(x, off, 64);
      if (l == 0) part[wv][v] = x;
    }
    __syncthreads();
    if (t < 26) {
      float s = part[0][t] + part[1][t] + part[2][t] + part[3][t];
      if (t < 25) ws[WS_M + a * 25 + t] = s; else ws[WS_C + a] = s;
    }
  } else {
    float acc = 0.f;
    for (int d = t; d < D_G; d += 256) { float b = bc[d]; acc += b * b; }
#pragma unroll
    for (int off = 32; off > 0; off >>= 1) acc += __shfl_down(acc, off, 64);
    if (l == 0) part[wv][0] = acc;
    __syncthreads();
    if (t == 0) ws[WS_BB] = part[0][0] + part[1][0] + part[2][0] + part[3][0];
  }
}

// PPAD rows, q, g2
__global__ void k_persample(const float* __restrict__ n, float* ws) {
  int j = blockIdx.x * 256 + threadIdx.x;
  if (j >= BATCH) return;
  const float* M  = ws + WS_M;
  const float* cv = ws + WS_C;
  float nr[25];
#pragma unroll
  for (int k = 0; k < 25; k++) nr[k] = n[j * 25 + k];
  float q = 0.f;
  for (int k2 = 0; k2 < 25; k2++) {
    float p = 0.f;
#pragma unroll
    for (int k1 = 0; k1 < 25; k1++) p += nr[k1] * M[k1 * 25 + k2];
    ws[WS_PPAD + j * KE + k2] = p;
    q += p * nr[k2];
  }
  float nc = 0.f;
#pragma unroll
  for (int k = 0; k < 25; k++) nc += nr[k] * cv[k];
  ws[WS_PPAD + j * KE + 25] = -0.5f * q;
  ws[WS_PPAD + j * KE + 26] = 0.f;
  ws[WS_PPAD + j * KE + 27] = 0.f;
  ws[WS_Q  + j] = q;
  ws[WS_G2 + j] = q + 2.f * nc + ws[WS_BB];
}

// prior GEMM: 256 prior-rows x 28 cols per block, K-split 16 over d.
// cols 0..24 = Wc rows, 25 = bc (s), 26 = p2 (wave0 extra), 27 unused.
// wave w handles cols 7w..7w+6; lane l handles rows {l, l+64, l+128, l+192}.
__global__ __launch_bounds__(256) void k_prior2(const float* __restrict__ prior, float* ws) {
  __shared__ float plds[256 * 34];   // prior tile [row][34] (32 d + pad)
  __shared__ float Wlds[28 * 34];    // weight tile [col][34]
  int t = threadIdx.x;
  int w0 = t >> 6, l = t & 63;
  int row0 = blockIdx.x * 256;
  int sp = blockIdx.y;
  int dstart = sp * 288;
  int nch = (sp == 15) ? 10 : 9;
  float acc[4][7];
  float p2acc[4];
#pragma unroll
  for (int r = 0; r < 4; r++) {
    p2acc[r] = 0.f;
#pragma unroll
    for (int c = 0; c < 7; c++) acc[r][c] = 0.f;
  }
  for (int ch = 0; ch < nch; ++ch) {
    int dbase = dstart + ch * 32;
    __syncthreads();
    // stage prior tile: 32 passes, 8 rows x 32 d each, coalesced
#pragma unroll 4
    for (int p = 0; p < 32; p++) {
      int row = p * 8 + (t >> 5);
      int dd = t & 31;
      int gd = dbase + dd;
      float v = (gd < D_G) ? prior[(size_t)(row0 + row) * D_G + gd] : 0.f;
      plds[row * 34 + dd] = v;
    }
    // stage weight tile
    for (int idx = t; idx < 28 * 32; idx += 256) {
      int k = idx >> 5, dd = idx & 31;
      int gd = dbase + dd;
      float v = 0.f;
      if (gd < D_G) {
        if (k < 25)      v = ws[WS_WCAT + k * DGP + gd];
        else if (k == 25) v = ws[WS_BCAT + gd];
      }
      Wlds[k * 34 + dd] = v;
    }
    __syncthreads();
#pragma unroll 4
    for (int d2 = 0; d2 < 16; d2++) {
      int dd = 2 * d2;
      float2 pv[4];
#pragma unroll
      for (int r = 0; r < 4; r++)
        pv[r] = *(const float2*)&plds[(l + 64 * r) * 34 + dd];
      float2 wv[7];
#pragma unroll
      for (int c = 0; c < 7; c++)
        wv[c] = *(const float2*)&Wlds[(7 * w0 + c) * 34 + dd];
#pragma unroll
      for (int r = 0; r < 4; r++)
#pragma unroll
        for (int c = 0; c < 7; c++)
          acc[r][c] = fmaf(pv[r].x, wv[c].x, fmaf(pv[r].y, wv[c].y, acc[r][c]));
      if (w0 == 0) {
#pragma unroll
        for (int r = 0; r < 4; r++)
          p2acc[r] = fmaf(pv[r].x, pv[r].x, fmaf(pv[r].y, pv[r].y, p2acc[r]));
      }
    }
  }
  // coalesced partial stores: RACCP[sp][col][row]
  float* RP = ws + WS_RACCP + (size_t)sp * 28 * BATCH;
#pragma unroll
  for (int c = 0; c < 7; c++) {
    int col = 7 * w0 + c;
    if (w0 == 3 && c >= 5) continue;   // cols 26,27 reserved
#pragma unroll
    for (int r = 0; r < 4; r++)
      RP[(size_t)col * BATCH + row0 + l + 64 * r] = acc[r][c];
  }
  if (w0 == 0) {
#pragma unroll
    for (int r = 0; r < 4; r++)
      RP[(size_t)26 * BATCH + row0 + l + 64 * r] = p2acc[r];
  }
}

// reduce the 16 K-splits, assemble RPAD rows
__global__ __launch_bounds__(256) void k_prior_fin(float* ws) {
  int j = blockIdx.x * 256 + threadIdx.x;
  float r[27];
#pragma unroll
  for (int k = 0; k < 27; k++) r[k] = 0.f;
  for (int sp = 0; sp < 16; sp++) {
    const float* RP = ws + WS_RACCP + (size_t)sp * 28 * BATCH;
#pragma unroll
    for (int k = 0; k < 27; k++) r[k] += RP[(size_t)k * BATCH + j];
  }
#pragma unroll
  for (int k = 0; k < 25; k++) ws[WS_RPAD + (size_t)j * KE + k] = r[k];
  ws[WS_RPAD + (size_t)j * KE + 25] = -0.5f * (r[26] - 2.f * r[25]);
  ws[WS_RPAD + (size_t)j * KE + 26] = 0.f;
  ws[WS_RPAD + (size_t)j * KE + 27] = 0.f;
}

// min over i of (alpha_i + beta_j - 2 A_i.n_j), clamped >= 0.
// 128-row i-slice in LDS; wave-uniform row broadcast feeds 2 j-chains/thread.
template <int SKIP>
__global__ __launch_bounds__(256) void k_pair(const float* __restrict__ APAD,
                                              const float* __restrict__ Bn,
                                              const float* __restrict__ beta,
                                              unsigned int* __restrict__ outm) {
  __shared__ float rows[128 * KE];
  int t = threadIdx.x;
  int jbase = blockIdx.y * 128;
  {
    const float4* src = (const float4*)(APAD + (size_t)jbase * KE);
    float4* dst = (float4*)rows;
    for (int idx = t; idx < 128 * KE / 4; idx += 256) dst[idx] = src[idx];
  }
  int j0 = blockIdx.x * 512 + t;
  int j1 = j0 + 256;
  float nx0[25], nx1[25];
#pragma unroll
  for (int k = 0; k < 25; k++) { nx0[k] = Bn[j0 * 25 + k]; nx1[k] = Bn[j1 * 25 + k]; }
  float bj0 = beta[j0], bj1 = beta[j1];
  float mn0 = 3.402823466e38f, mn1 = 3.402823466e38f;
  __syncthreads();
#pragma unroll 2
  for (int it = 0; it < 128; ++it) {
    const float* row = rows + it * KE;
    float a0 = row[25], a1 = row[25];
#pragma unroll
    for (int k = 0; k < 25; k++) { a0 = fmaf(row[k], nx0[k], a0); a1 = fmaf(row[k], nx1[k], a1); }
    float sq0 = fmaxf(fmaf(-2.f, a0, bj0), 0.f);
    float sq1 = fmaxf(fmaf(-2.f, a1, bj1), 0.f);
    int i = jbase + it;
    bool sk0 = SKIP && (i == j0);
    bool sk1 = SKIP && (i == j1);
    mn0 = sk0 ? mn0 : fminf(mn0, sq0);
    mn1 = sk1 ? mn1 : fminf(mn1, sq1);
  }
  atomicMin(&outm[j0], __float_as_uint(mn0));
  atomicMin(&outm[j1], __float_as_uint(mn1));
}

// decode phase 1: h1[s,r] = elu( sum_k nh[k] * (w~.z + b~) ), weights fully in LDS
__global__ __launch_bounds__(256) void kd1v2(const float* __restrict__ n, const float* __restrict__ z,
                                             const float* __restrict__ w1W, const float* __restrict__ w1b,
                                             const float* __restrict__ b1W, const float* __restrict__ b1b,
                                             float* __restrict__ h1t) {
  __shared__ float W1lds[8 * 128];   // [rr][k*4 + d]: d<3 = w~, d=3 = b~1
  int t = threadIdx.x;
  int rb = blockIdx.y * 8;
  for (int idx = t; idx < 1024; idx += 256) {
    int rr = idx >> 7, rem = idx & 127, k = rem >> 2, d = rem & 3;
    float v = 0.f;
    if (k < 26) {
      int r = rb + rr;
      if (d < 3) v = (k < 25) ? w1W[k * 192 + r * 3 + d] : w1b[r * 3 + d];
      else       v = (k < 25) ? b1W[k * 64 + r]          : b1b[r];
    }
    W1lds[idx] = v;
  }
  int s = blockIdx.x * 256 + t;
  float nx[26];
#pragma unroll
  for (int k = 0; k < 25; k++) nx[k] = n[s * 25 + k];
  nx[25] = 1.f;
  float z0 = z[s * 3], z1 = z[s * 3 + 1], z2 = z[s * 3 + 2];
  __syncthreads();
#pragma unroll
  for (int rr = 0; rr < 8; rr++) {
    float acc = 0.f;
#pragma unroll
    for (int k = 0; k < 26; k++) {
      float4 wv = *(const float4*)&W1lds[rr * 128 + k * 4];
      float v = fmaf(wv.x, z0, fmaf(wv.y, z1, fmaf(wv.z, z2, wv.w)));
      acc = fmaf(nx[k], v, acc);
    }
    h1t[(size_t)(rb + rr) * BATCH + s] = eluf(acc);
  }
}

// decode phase 2: register-tiled GEMM y[(rr,k)][s] = sum_c w~2 * h1, then
// LDS epilogue h2[s,r] = elu( sum_k nh*y + sum_k nh*b~2 )
__global__ __launch_bounds__(256) void kd2v2(const float* __restrict__ n,
                                             const float* __restrict__ w2W, const float* __restrict__ w2b,
                                             const float* __restrict__ b2W, const float* __restrict__ b2b,
                                             const float* __restrict__ h1t, float* __restrict__ h2t) {
  __shared__ float W2lds[104 * 66];  // row = rr*26 + k, cols c
  __shared__ float h1lds[64 * 66];   // [s][c]
  __shared__ float nlds[26 * 66];    // [k][s]
  __shared__ float b2lds[26 * 4];    // [k][rr]
  __shared__ float redlds[8 * 66];   // [rowg][s]
  int t = threadIdx.x;
  int s0 = blockIdx.x * 64;
  int r0 = blockIdx.y * 4;
#pragma unroll
  for (int rr = 0; rr < 4; rr++) {
    for (int idx = t; idx < 26 * 64; idx += 256) {
      int k = idx >> 6, c = idx & 63;
      float v = (k < 25) ? w2W[k * 4096 + (r0 + rr) * 64 + c] : w2b[(r0 + rr) * 64 + c];
      W2lds[(rr * 26 + k) * 66 + c] = v;
    }
  }
  for (int idx = t; idx < 64 * 64; idx += 256) {
    int c = idx >> 6, s = idx & 63;
    h1lds[s * 66 + c] = h1t[(size_t)c * BATCH + s0 + s];
  }
  for (int idx = t; idx < 26 * 64; idx += 256) {
    int k = idx >> 6, s = idx & 63;
    nlds[k * 66 + s] = (k < 25) ? n[(s0 + s) * 25 + k] : 1.f;
  }
  for (int idx = t; idx < 104; idx += 256) {
    int k = idx >> 2, rr = idx & 3;
    b2lds[idx] = (k < 25) ? b2W[k * 64 + r0 + rr] : b2b[r0 + rr];
  }
  __syncthreads();
  int rowg = t >> 5;        // 0..7
  int sg = t & 31;          // 0..31
  int kbase = (rowg & 1) * 13;
  int rr = rowg >> 1;       // 0..3
  float y[13][2];
#pragma unroll
  for (int kk = 0; kk < 13; kk++) { y[kk][0] = 0.f; y[kk][1] = 0.f; }
#pragma unroll 4
  for (int c2 = 0; c2 < 32; c2++) {
    int c = 2 * c2;
    float2 h0 = *(const float2*)&h1lds[(2 * sg) * 66 + c];
    float2 h1v = *(const float2*)&h1lds[(2 * sg + 1) * 66 + c];
#pragma unroll
    for (int kk = 0; kk < 13; kk++) {
      float2 wv = *(const float2*)&W2lds[(rr * 26 + kbase + kk) * 66 + c];
      y[kk][0] = fmaf(wv.x, h0.x, fmaf(wv.y, h0.y, y[kk][0]));
      y[kk][1] = fmaf(wv.x, h1v.x, fmaf(wv.y, h1v.y, y[kk][1]));
    }
  }
  float p0 = 0.f, p1 = 0.f;
#pragma unroll
  for (int kk = 0; kk < 13; kk++) {
    float2 nk = *(const float2*)&nlds[(kbase + kk) * 66 + 2 * sg];
    p0 = fmaf(nk.x, y[kk][0], p0);
    p1 = fmaf(nk.y, y[kk][1], p1);
  }
  redlds[rowg * 66 + 2 * sg]     = p0;
  redlds[rowg * 66 + 2 * sg + 1] = p1;
  __syncthreads();
  {
    int rr2 = t >> 6, s = t & 63;
    float bias = 0.f;
#pragma unroll
    for (int k = 0; k < 26; k++) bias = fmaf(nlds[k * 66 + s], b2lds[k * 4 + rr2], bias);
    float v = redlds[(2 * rr2) * 66 + s] + redlds[(2 * rr2 + 1) * 66 + s] + bias;
    h2t[(size_t)(r0 + rr2) * BATCH + s0 + s] = eluf(v);
  }
}

// decode phase 3: z_hat row r, recon partial
__global__ __launch_bounds__(256) void kd3v2(const float* __restrict__ n, const float* __restrict__ znext,
                                             const float* __restrict__ w3W, const float* __restrict__ w3b,
                                             const float* __restrict__ b3W, const float* __restrict__ b3b,
                                             const float* __restrict__ h2t,
                                             float* __restrict__ out, float* __restrict__ accum) {
  __shared__ float W3lds[26 * 68];
  __shared__ float b3lds[26];
  int t = threadIdx.x;
  int r = blockIdx.y;
  int s = blockIdx.x * 256 + t;
  for (int idx = t; idx < 26 * 64; idx += 256) {
    int k = idx >> 6, c = idx & 63;
    W3lds[k * 68 + c] = (k < 25) ? w3W[k * 192 + r * 64 + c] : w3b[r * 64 + c];
  }
  if (t < 26) b3lds[t] = (t < 25) ? b3W[t * 3 + r] : b3b[r];
  float h2r[64];
#pragma unroll
  for (int c = 0; c < 64; c++) h2r[c] = h2t[(size_t)c * BATCH + s];
  float nx[26];
#pragma unroll
  for (int k = 0; k < 25; k++) nx[k] = n[s * 25 + k];
  nx[25] = 1.f;
  __syncthreads();
  float acc = 0.f;
  for (int k = 0; k < 26; k++) {
    float inner = b3lds[k];
#pragma unroll
    for (int c = 0; c < 64; c++) inner = fmaf(W3lds[k * 68 + c], h2r[c], inner);
    acc = fmaf(nx[k], inner, acc);
  }
  out[2 + s * 3 + r] = acc;
  float dz = acc - znext[s * 3 + r];
  float v = dz * dz;
#pragma unroll
  for (int off = 32; off > 0; off >>= 1) v += __shfl_down(v, off, 64);
  if ((t & 63) == 0) atomicAdd(accum, v);
}

__global__ void k_finish(float* ws, float* __restrict__ out) {
  __shared__ float sred[256];
  int t = threadIdx.x;
  float part = 0.f;
  for (int j = t; j < BATCH; j += 256) {
    float wp2 = ws[WS_WP2 + j];
    float ww2 = ws[WS_WW2 + j];
    float wp = sqrtf(wp2 + 1e-8f);
    float ww = sqrtf(ww2 + 1e-8f);
    part += logf(wp / (ww + 1e-8f) + 1e-8f);
  }
  sred[t] = part; __syncthreads();
  for (int off = 128; off > 0; off >>= 1) { if (t < off) sred[t] += sred[t + off]; __syncthreads(); }
  if (t == 0) {
    float kl = sred[0] / (float)BATCH * (float)D_G + logf((float)BATCH / (float)(BATCH - 1));
    out[0] = ws[WS_ACC] / (float)BATCH;
    out[1] = kl;
  }
}

extern "C" void kernel_launch(void* const* d_in, const int* in_sizes, int n_in,
                              void* d_out, int out_size, void* d_ws, size_t ws_size,
                              hipStream_t stream) {
  (void)in_sizes; (void)n_in; (void)out_size; (void)ws_size;
  const float* z     = (const float*)d_in[0];
  const float* znext = (const float*)d_in[1];
  const float* n     = (const float*)d_in[2];
  const float* prior = (const float*)d_in[3];
  const float* w1W = (const float*)d_in[4];  const float* w1b = (const float*)d_in[5];
  const float* b1W = (const float*)d_in[6];  const float* b1b = (const float*)d_in[7];
  const float* w2W = (const float*)d_in[8];  const float* w2b = (const float*)d_in[9];
  const float* b2W = (const float*)d_in[10]; const float* b2b = (const float*)d_in[11];
  const float* w3W = (const float*)d_in[12]; const float* w3b = (const float*)d_in[13];
  const float* b3W = (const float*)d_in[14]; const float* b3b = (const float*)d_in[15];
  float* out = (float*)d_out;
  float* ws  = (float*)d_ws;

  k_init<<<dim3(65), dim3(256), 0, stream>>>(ws);
  k_build<<<dim3((KN * D_G + 255) / 256), dim3(256), 0, stream>>>(
      w1W, w1b, b1W, b1b, w2W, w2b, b2W, b2b, w3W, w3b, b3W, b3b, ws);
  k_M<<<dim3(26), dim3(256), 0, stream>>>(ws);
  k_persample<<<dim3(32), dim3(256), 0, stream>>>(n, ws);
  k_prior2<<<dim3(32, 16), dim3(256), 0, stream>>>(prior, ws);
  k_prior_fin<<<dim3(32), dim3(256), 0, stream>>>(ws);
  k_pair<1><<<dim3(16, 64), dim3(256), 0, stream>>>(ws + WS_PPAD, n, ws + WS_Q,
                                                    (unsigned int*)(ws + WS_WW2));
  k_pair<0><<<dim3(16, 64), dim3(256), 0, stream>>>(ws + WS_RPAD, n, ws + WS_G2,
                                                    (unsigned int*)(ws + WS_WP2));
  kd1v2<<<dim3(32, 8), dim3(256), 0, stream>>>(n, z, w1W, w1b, b1W, b1b, ws + WS_H1T);
  kd2v2<<<dim3(128, 16), dim3(256), 0, stream>>>(n, w2W, w2b, b2W, b2b, ws + WS_H1T, ws + WS_H2T);
  kd3v2<<<dim3(32, 3), dim3(256), 0, stream>>>(n, znext, w3W, w3b, b3W, b3b,
                                               ws + WS_H2T, out, ws + WS_ACC);
  k_finish<<<dim3(1), dim3(256), 0, stream>>>(ws, out);
}